// Round 3
// baseline (200.069 us; speedup 1.0000x reference)
//
#include <hip/hip_runtime.h>

typedef unsigned short u16;
typedef unsigned int   u32;

#define B_ 2
#define C_ 128
#define T_ 512
#define F_ 64
#define H_ 32
#define D_ 32

// ---- d_out scratch (float offsets): xm1/xf1 fp32 intermediates live in d_out ----
#define XM1_OUT 0u
#define XF1_OUT 2097152u

// ---- d_ws layout (float offsets) — total 1,168,674 floats = 4.67 MB ----
#define CORR_OFF 0u          // padded corr: [b][h][518][34]
#define CORR_N   1127168u
#define WQ_OFF   1127168u    // softmax weights [b][512][32]
#define WT_OFF   1159936u    // fp32 small weights (8737 floats)
#define FLAG_OFF 1168673u    // u32: 0 = bf16 inputs, 1 = fp32 inputs
// within WT: w1:0  b1:4096  w2:4128  b2:8224  wc:8256  bc:8736

// scrubbed decodes: any exp==0xFF (Inf/NaN) -> 0
__device__ __forceinline__ float scrub_u(u32 v){
  return ((v & 0x7F800000u) == 0x7F800000u) ? 0.f : __uint_as_float(v);
}
__device__ __forceinline__ float bf_lo(u32 u){ return scrub_u(u << 16); }
__device__ __forceinline__ float bf_hi(u32 u){ return scrub_u(u & 0xffff0000u); }
__device__ __forceinline__ float bf1(u16 v){ return scrub_u(((u32)v) << 16); }
__device__ __forceinline__ float f32s(float x){ return scrub_u(__float_as_uint(x)); }
__device__ __forceinline__ u16 f2bf(float x){
  u32 u = __float_as_uint(x);
  u32 r = u + 0x7fffu + ((u >> 16) & 1u);
  return (u16)(r >> 16);
}

// ---------------- KD: runtime input-dtype detection ----------------
__global__ __launch_bounds__(256) void kd_detect(const u16* __restrict__ w1, u32* __restrict__ flag){
  __shared__ int cnt;
  if (threadIdx.x == 0) cnt = 0;
  __syncthreads();
  int c = 0;
  for (int i = threadIdx.x * 2; i < 4096; i += 512){   // even u16 indices
    u32 e = ((u32)w1[i] >> 7) & 0xFFu;                 // bf16 exponent field
    if (e >= 0xBFu) c++;                               // |v| >= 2^64: impossible for real bf16 w1
  }
  atomicAdd(&cnt, c);
  __syncthreads();
  if (threadIdx.x == 0) flag[0] = (cnt > 16) ? 1u : 0u;
}

// ---------------- K0: zero corr halo + convert small weights to fp32 ----------------
__global__ __launch_bounds__(256) void k0_init(const void* __restrict__ w1, const void* __restrict__ b1,
                                               const void* __restrict__ w2, const void* __restrict__ b2,
                                               const void* __restrict__ wc, const void* __restrict__ bc,
                                               float* __restrict__ ws, const u32* __restrict__ flag){
  u32 i = blockIdx.x * 256u + threadIdx.x;
  float* cp = ws + CORR_OFF;
  for (u32 k = i; k < CORR_N; k += gridDim.x * 256u) cp[k] = 0.f;
  float* wt = ws + WT_OFF;
  u32 isf = *flag;
  if (!isf){
    const u16* W1=(const u16*)w1; const u16* B1=(const u16*)b1;
    const u16* W2=(const u16*)w2; const u16* B2=(const u16*)b2;
    const u16* WC=(const u16*)wc; const u16* BC=(const u16*)bc;
    if (i < 4096u) wt[i]        = bf1(W1[i]);
    if (i < 32u)   wt[4096u+i]  = bf1(B1[i]);
    if (i < 4096u) wt[4128u+i]  = bf1(W2[i]);
    if (i < 32u)   wt[8224u+i]  = bf1(B2[i]);
    if (i < 480u)  wt[8256u+i]  = bf1(WC[i]);
    if (i == 0u)   wt[8736u]    = bf1(BC[0]);
  } else {
    const float* W1=(const float*)w1; const float* B1=(const float*)b1;
    const float* W2=(const float*)w2; const float* B2=(const float*)b2;
    const float* WC=(const float*)wc; const float* BC=(const float*)bc;
    if (i < 4096u) wt[i]        = f32s(W1[i]);
    if (i < 32u)   wt[4096u+i]  = f32s(B1[i]);
    if (i < 4096u) wt[4128u+i]  = f32s(W2[i]);
    if (i < 32u)   wt[8224u+i]  = f32s(B2[i]);
    if (i < 480u)  wt[8256u+i]  = f32s(WC[i]);
    if (i == 0u)   wt[8736u]    = f32s(BC[0]);
  }
}

// ---------------- K1: projections xm1 = W1^T @ xm, xf1 = W2^T @ xf (+bias) ----------------
__global__ __launch_bounds__(256) void k1_proj(const void* __restrict__ xm, const void* __restrict__ xf,
                                               const float* __restrict__ wt, const u32* __restrict__ flag,
                                               float* __restrict__ xm1, float* __restrict__ xf1){
  int bt  = blockIdx.x >> 6;          // 0..3
  int b   = bt >> 1, sel = bt & 1;
  int m0  = (((blockIdx.x & 63) << 8) + threadIdx.x) * 2;   // [0, 32768)
  const void* Xv = sel ? xf : xm;
  const float* W = wt + (sel ? 4128 : 0);
  const float* bias = wt + (sel ? 8224 : 4096);
  u32 isf = *flag;

  float acc0[H_], acc1[H_];
#pragma unroll
  for (int h = 0; h < H_; h++){ acc0[h] = 0.f; acc1[h] = 0.f; }

  if (!isf){
    const u16* X = (const u16*)Xv + (size_t)b * (C_*T_*F_);
    for (int c = 0; c < C_; c++){
      u32 u = *(const u32*)(X + (size_t)c * (T_*F_) + m0);
      float x0 = bf_lo(u), x1 = bf_hi(u);
#pragma unroll
      for (int h = 0; h < H_; h++){
        float wv = W[c * H_ + h];
        acc0[h] += x0 * wv;
        acc1[h] += x1 * wv;
      }
    }
  } else {
    const float* X = (const float*)Xv + (size_t)b * (C_*T_*F_);
    for (int c = 0; c < C_; c++){
      float2 xv = *(const float2*)(X + (size_t)c * (T_*F_) + m0);
      float x0 = f32s(xv.x), x1 = f32s(xv.y);
#pragma unroll
      for (int h = 0; h < H_; h++){
        float wv = W[c * H_ + h];
        acc0[h] += x0 * wv;
        acc1[h] += x1 * wv;
      }
    }
  }
  float* O = (sel ? xf1 : xm1) + (size_t)b * (H_*T_*F_);
#pragma unroll
  for (int h = 0; h < H_; h++){
    float bv = bias[h];
    *(float2*)(O + (size_t)h * (T_*F_) + m0) = make_float2(acc0[h] + bv, acc1[h] + bv);
  }
}

// ---------------- K2: corr[b,h,t,d] = sum_f xm1[b,h,t,f] * xf1[b,h,t+d-31,f] ----------------
__global__ __launch_bounds__(256) void k2_corr(const float* __restrict__ xm1, const float* __restrict__ xf1,
                                               float* __restrict__ corr_pad){
  int blk = blockIdx.x;
  int tt = blk & 7, h = (blk >> 3) & 31, b = blk >> 8;
  int t0 = tt * 64;
  const float* A  = xm1 + ((size_t)(b*H_ + h)) * (T_*F_);
  const float* Bm = xf1 + ((size_t)(b*H_ + h)) * (T_*F_);

  __shared__ float Al[64*68];
  __shared__ float Bl[95*68];
  int tid = threadIdx.x;

  for (int idx = tid; idx < 64*16; idx += 256){
    int r = idx >> 4, q = idx & 15;
    *(float4*)(Al + r*68 + q*4) = *(const float4*)(A + (size_t)(t0 + r)*F_ + q*4);
  }
  for (int idx = tid; idx < 95*16; idx += 256){
    int r = idx >> 4, q = idx & 15;
    int gr = t0 - 31 + r;
    float4 v = make_float4(0.f,0.f,0.f,0.f);
    if (gr >= 0) v = *(const float4*)(Bm + (size_t)gr*F_ + q*4);
    *(float4*)(Bl + r*68 + q*4) = v;
  }
  __syncthreads();

  int tl = tid >> 2, dg = tid & 3;     // 64 t x 4 d-groups (8 d each)
  float acc[8];
#pragma unroll
  for (int j = 0; j < 8; j++) acc[j] = 0.f;

  for (int fq = 0; fq < 16; fq++){
    float4 a = *(const float4*)(Al + tl*68 + fq*4);
#pragma unroll
    for (int j = 0; j < 8; j++){
      float4 bv = *(const float4*)(Bl + (tl + dg*8 + j)*68 + fq*4);
      acc[j] += a.x*bv.x + a.y*bv.y + a.z*bv.z + a.w*bv.w;
    }
  }
  float* o = corr_pad + ((size_t)(b*H_ + h))*(518*34) + (size_t)(t0 + tl + 3)*34 + (dg*8 + 1);
#pragma unroll
  for (int j = 0; j < 8; j++) o[j] = acc[j];
}

// ---------------- K3: 5x3 conv over (t,d) summing h, + bc, causal mask, softmax over d ----------------
__global__ __launch_bounds__(256) void k3_conv_softmax(const float* __restrict__ corr_pad,
                                                       const float* __restrict__ wt,
                                                       float* __restrict__ wq){
  int b  = blockIdx.x >> 6;
  int t0 = (blockIdx.x & 63) * 8;
  int tid = threadIdx.x;
  int tl = tid >> 5, d = tid & 31;
  int t = t0 + tl;

  const float* wcf = wt + 8256;
  float val = wt[8736];
  const float* cp = corr_pad + (size_t)b * (H_*518*34);

  for (int h = 0; h < H_; h++){
    const float* cph = cp + (size_t)h*(518*34) + (size_t)t*34 + d;
    const float* wch = wcf + h*15;
#pragma unroll
    for (int kh = 0; kh < 5; kh++){
#pragma unroll
      for (int kw = 0; kw < 3; kw++){
        val += cph[kh*34 + kw] * wch[kh*3 + kw];
      }
    }
  }
  if (t + d < D_ - 1) val = -1e13f;

  float m = val;
#pragma unroll
  for (int off = 16; off > 0; off >>= 1) m = fmaxf(m, __shfl_xor(m, off));
  float e = __expf(val - m);
  float s = e;
#pragma unroll
  for (int off = 16; off > 0; off >>= 1) s += __shfl_xor(s, off);

  wq[((size_t)b*T_ + t)*D_ + d] = e / s;
}

// ---------------- K4: out[b,c,t,f] = sum_d w[b,t,d] * xf[b,c,t+d-31,f] ----------------
__global__ __launch_bounds__(256) void k4_out(const void* __restrict__ xf, const float* __restrict__ wq,
                                              const u32* __restrict__ flag, void* __restrict__ out){
  int blk = blockIdx.x;
  int tt = blk & 7, c = (blk >> 3) & 127, b = blk >> 10;
  int t0 = tt * 64;
  u32 isf = *flag;

  __shared__ float xfl[95*68];
  __shared__ float wl[64*33];
  int tid = threadIdx.x;

  if (!isf){
    const u16* Xf = (const u16*)xf + ((size_t)(b*C_ + c)) * (T_*F_);
    for (int idx = tid; idx < 95*16; idx += 256){
      int r = idx >> 4, q = idx & 15;
      int gr = t0 - 31 + r;
      float4 v = make_float4(0.f,0.f,0.f,0.f);
      if (gr >= 0){
        uint2 u = *(const uint2*)(Xf + (size_t)gr*F_ + q*4);
        v.x = bf_lo(u.x); v.y = bf_hi(u.x); v.z = bf_lo(u.y); v.w = bf_hi(u.y);
      }
      *(float4*)(xfl + r*68 + q*4) = v;
    }
  } else {
    const float* Xf = (const float*)xf + ((size_t)(b*C_ + c)) * (T_*F_);
    for (int idx = tid; idx < 95*16; idx += 256){
      int r = idx >> 4, q = idx & 15;
      int gr = t0 - 31 + r;
      float4 v = make_float4(0.f,0.f,0.f,0.f);
      if (gr >= 0){
        float4 u = *(const float4*)(Xf + (size_t)gr*F_ + q*4);
        v.x = f32s(u.x); v.y = f32s(u.y); v.z = f32s(u.z); v.w = f32s(u.w);
      }
      *(float4*)(xfl + r*68 + q*4) = v;
    }
  }
  for (int idx = tid; idx < 64*8; idx += 256){
    int r = idx >> 3, q = idx & 7;
    float4 v = *(const float4*)(wq + ((size_t)b*T_ + t0 + r)*D_ + q*4);
    wl[r*33 + q*4 + 0] = v.x; wl[r*33 + q*4 + 1] = v.y;
    wl[r*33 + q*4 + 2] = v.z; wl[r*33 + q*4 + 3] = v.w;
  }
  __syncthreads();

  int tg = tid >> 4, q = tid & 15;   // 16 t-groups (4 t each) x 16 f-quads
  float4 acc[4];
#pragma unroll
  for (int j = 0; j < 4; j++) acc[j] = make_float4(0.f,0.f,0.f,0.f);

#pragma unroll
  for (int rr = 0; rr < 35; rr++){
    float4 xv = *(const float4*)(xfl + (tg*4 + rr)*68 + q*4);
#pragma unroll
    for (int j = 0; j < 4; j++){
      int d = rr - j;
      if (d >= 0 && d < D_){
        float wv = wl[(tg*4 + j)*33 + d];
        acc[j].x += wv * xv.x; acc[j].y += wv * xv.y;
        acc[j].z += wv * xv.z; acc[j].w += wv * xv.w;
      }
    }
  }
  if (!isf){
#pragma unroll
    for (int j = 0; j < 4; j++){
      int t = t0 + tg*4 + j;
      u16* O = (u16*)out + (((size_t)(b*C_ + c))*T_ + t)*F_ + q*4;
      u32 lo = (u32)f2bf(acc[j].x) | ((u32)f2bf(acc[j].y) << 16);
      u32 hi = (u32)f2bf(acc[j].z) | ((u32)f2bf(acc[j].w) << 16);
      *(uint2*)O = make_uint2(lo, hi);
    }
  } else {
#pragma unroll
    for (int j = 0; j < 4; j++){
      int t = t0 + tg*4 + j;
      float* O = (float*)out + (((size_t)(b*C_ + c))*T_ + t)*F_ + q*4;
      *(float4*)O = acc[j];
    }
  }
}

extern "C" void kernel_launch(void* const* d_in, const int* in_sizes, int n_in,
                              void* d_out, int out_size, void* d_ws, size_t ws_size,
                              hipStream_t stream) {
  const void* xm = d_in[0];
  const void* xf = d_in[1];
  float* ws = (float*)d_ws;
  u32* flag = (u32*)(ws + FLAG_OFF);

  // xm1/xf1 fp32 intermediates live in d_out (bf16 out: exactly 16 MB; fp32 out: 33 MB).
  // K4 reads only xf/wq, then overwrites d_out with the final result.
  float* xm1 = (float*)d_out + XM1_OUT;
  float* xf1 = (float*)d_out + XF1_OUT;

  hipLaunchKernelGGL(kd_detect, dim3(1), dim3(256), 0, stream, (const u16*)d_in[2], flag);
  hipLaunchKernelGGL(k0_init, dim3(1024), dim3(256), 0, stream, d_in[2], d_in[3], d_in[4],
                     d_in[5], d_in[6], d_in[7], ws, flag);
  hipLaunchKernelGGL(k1_proj, dim3(256), dim3(256), 0, stream, xm, xf, ws + WT_OFF, flag, xm1, xf1);
  hipLaunchKernelGGL(k2_corr, dim3(512), dim3(256), 0, stream, xm1, xf1, ws + CORR_OFF);
  hipLaunchKernelGGL(k3_conv_softmax, dim3(128), dim3(256), 0, stream, ws + CORR_OFF,
                     ws + WT_OFF, ws + WQ_OFF);
  hipLaunchKernelGGL(k4_out, dim3(2048), dim3(256), 0, stream, xf, ws + WQ_OFF, flag, d_out);
}

// Round 4
// 185.541 us; speedup vs baseline: 1.0783x; 1.0783x over previous
//
#include <hip/hip_runtime.h>

typedef unsigned short u16;
typedef unsigned int   u32;

#define B_ 2
#define C_ 128
#define T_ 512
#define F_ 64
#define H_ 32
#define D_ 32

// ---- d_out scratch (float offsets): xm1/xf1 fp32 intermediates live in d_out ----
#define XM1_OUT 0u
#define XF1_OUT 2097152u

// ---- d_ws layout (float offsets) ----
#define CORR_OFF 0u          // padded corr: [b][h][518][34]
#define CORR_N   1127168u
#define WQ_OFF   1127168u    // softmax weights [b][512][32]
#define WT_OFF   1159936u    // fp32 small weights (8737 floats)
#define FLAG_OFF 1168673u    // u32: 0 = bf16 inputs, 1 = fp32 inputs
// within WT: w1:0  b1:4096  w2:4128  b2:8224  wc:8256  bc:8736

__device__ __forceinline__ float scrub_u(u32 v){
  return ((v & 0x7F800000u) == 0x7F800000u) ? 0.f : __uint_as_float(v);
}
__device__ __forceinline__ float bf_lo(u32 u){ return scrub_u(u << 16); }
__device__ __forceinline__ float bf_hi(u32 u){ return scrub_u(u & 0xffff0000u); }
__device__ __forceinline__ float bf1(u16 v){ return scrub_u(((u32)v) << 16); }
__device__ __forceinline__ float f32s(float x){ return scrub_u(__float_as_uint(x)); }
__device__ __forceinline__ u16 f2bf(float x){
  u32 u = __float_as_uint(x);
  u32 r = u + 0x7fffu + ((u >> 16) & 1u);
  return (u16)(r >> 16);
}

// ---------------- KD: runtime input-dtype detection ----------------
__global__ __launch_bounds__(256) void kd_detect(const u16* __restrict__ w1, u32* __restrict__ flag){
  __shared__ int cnt;
  if (threadIdx.x == 0) cnt = 0;
  __syncthreads();
  int c = 0;
  for (int i = threadIdx.x * 2; i < 4096; i += 512){
    u32 e = ((u32)w1[i] >> 7) & 0xFFu;
    if (e >= 0xBFu) c++;
  }
  atomicAdd(&cnt, c);
  __syncthreads();
  if (threadIdx.x == 0) flag[0] = (cnt > 16) ? 1u : 0u;
}

// ---------------- K0: zero corr halo + convert small weights to fp32 ----------------
__global__ __launch_bounds__(256) void k0_init(const void* __restrict__ w1, const void* __restrict__ b1,
                                               const void* __restrict__ w2, const void* __restrict__ b2,
                                               const void* __restrict__ wc, const void* __restrict__ bc,
                                               float* __restrict__ ws, const u32* __restrict__ flag){
  u32 i = blockIdx.x * 256u + threadIdx.x;
  float* cp = ws + CORR_OFF;
  for (u32 k = i; k < CORR_N; k += gridDim.x * 256u) cp[k] = 0.f;
  float* wt = ws + WT_OFF;
  u32 isf = *flag;
  if (!isf){
    const u16* W1=(const u16*)w1; const u16* B1=(const u16*)b1;
    const u16* W2=(const u16*)w2; const u16* B2=(const u16*)b2;
    const u16* WC=(const u16*)wc; const u16* BC=(const u16*)bc;
    if (i < 4096u) wt[i]        = bf1(W1[i]);
    if (i < 32u)   wt[4096u+i]  = bf1(B1[i]);
    if (i < 4096u) wt[4128u+i]  = bf1(W2[i]);
    if (i < 32u)   wt[8224u+i]  = bf1(B2[i]);
    if (i < 480u)  wt[8256u+i]  = bf1(WC[i]);
    if (i == 0u)   wt[8736u]    = bf1(BC[0]);
  } else {
    const float* W1=(const float*)w1; const float* B1=(const float*)b1;
    const float* W2=(const float*)w2; const float* B2=(const float*)b2;
    const float* WC=(const float*)wc; const float* BC=(const float*)bc;
    if (i < 4096u) wt[i]        = f32s(W1[i]);
    if (i < 32u)   wt[4096u+i]  = f32s(B1[i]);
    if (i < 4096u) wt[4128u+i]  = f32s(W2[i]);
    if (i < 32u)   wt[8224u+i]  = f32s(B2[i]);
    if (i < 480u)  wt[8256u+i]  = f32s(WC[i]);
    if (i == 0u)   wt[8736u]    = f32s(BC[0]);
  }
}

// ---------------- K1: projections, 16-deep load batching for MLP ----------------
__global__ __launch_bounds__(256) void k1_proj(const void* __restrict__ xm, const void* __restrict__ xf,
                                               const float* __restrict__ wt, const u32* __restrict__ flag,
                                               float* __restrict__ xm1, float* __restrict__ xf1){
  int bt  = blockIdx.x >> 6;          // 0..3
  int b   = bt >> 1, sel = bt & 1;
  int m0  = (((blockIdx.x & 63) << 8) + threadIdx.x) * 2;   // [0, 32768)
  const void* Xv = sel ? xf : xm;
  const float* W = wt + (sel ? 4128 : 0);
  const float* bias = wt + (sel ? 8224 : 4096);
  u32 isf = *flag;

  float acc0[H_], acc1[H_];
#pragma unroll
  for (int h = 0; h < H_; h++){ acc0[h] = 0.f; acc1[h] = 0.f; }

  if (!isf){
    const u16* X = (const u16*)Xv + (size_t)b * (C_*T_*F_);
    for (int c0 = 0; c0 < C_; c0 += 16){
      u32 xv[16];
#pragma unroll
      for (int u = 0; u < 16; u++)
        xv[u] = *(const u32*)(X + (size_t)(c0+u) * (T_*F_) + m0);
#pragma unroll
      for (int u = 0; u < 16; u++){
        float x0 = bf_lo(xv[u]), x1 = bf_hi(xv[u]);
        const float* Wr = W + (c0+u) * H_;
#pragma unroll
        for (int h = 0; h < H_; h++){
          float wv = Wr[h];
          acc0[h] += x0 * wv;
          acc1[h] += x1 * wv;
        }
      }
    }
  } else {
    const float* X = (const float*)Xv + (size_t)b * (C_*T_*F_);
    for (int c0 = 0; c0 < C_; c0 += 16){
      float2 xv[16];
#pragma unroll
      for (int u = 0; u < 16; u++)
        xv[u] = *(const float2*)(X + (size_t)(c0+u) * (T_*F_) + m0);
#pragma unroll
      for (int u = 0; u < 16; u++){
        float x0 = f32s(xv[u].x), x1 = f32s(xv[u].y);
        const float* Wr = W + (c0+u) * H_;
#pragma unroll
        for (int h = 0; h < H_; h++){
          float wv = Wr[h];
          acc0[h] += x0 * wv;
          acc1[h] += x1 * wv;
        }
      }
    }
  }
  float* O = (sel ? xf1 : xm1) + (size_t)b * (H_*T_*F_);
#pragma unroll
  for (int h = 0; h < H_; h++){
    float bv = bias[h];
    *(float2*)(O + (size_t)h * (T_*F_) + m0) = make_float2(acc0[h] + bv, acc1[h] + bv);
  }
}

// ---------------- K2: corr[b,h,t,d] = sum_f xm1[b,h,t,f] * xf1[b,h,t+d-31,f] ----------------
__global__ __launch_bounds__(256) void k2_corr(const float* __restrict__ xm1, const float* __restrict__ xf1,
                                               float* __restrict__ corr_pad){
  int blk = blockIdx.x;
  int tt = blk & 7, h = (blk >> 3) & 31, b = blk >> 8;
  int t0 = tt * 64;
  const float* A  = xm1 + ((size_t)(b*H_ + h)) * (T_*F_);
  const float* Bm = xf1 + ((size_t)(b*H_ + h)) * (T_*F_);

  __shared__ float Al[64*68];
  __shared__ float Bl[95*68];
  int tid = threadIdx.x;

  for (int idx = tid; idx < 64*16; idx += 256){
    int r = idx >> 4, q = idx & 15;
    *(float4*)(Al + r*68 + q*4) = *(const float4*)(A + (size_t)(t0 + r)*F_ + q*4);
  }
  for (int idx = tid; idx < 95*16; idx += 256){
    int r = idx >> 4, q = idx & 15;
    int gr = t0 - 31 + r;
    float4 v = make_float4(0.f,0.f,0.f,0.f);
    if (gr >= 0) v = *(const float4*)(Bm + (size_t)gr*F_ + q*4);
    *(float4*)(Bl + r*68 + q*4) = v;
  }
  __syncthreads();

  int tl = tid >> 2, dg = tid & 3;
  float acc[8];
#pragma unroll
  for (int j = 0; j < 8; j++) acc[j] = 0.f;

  for (int fq = 0; fq < 16; fq++){
    float4 a = *(const float4*)(Al + tl*68 + fq*4);
#pragma unroll
    for (int j = 0; j < 8; j++){
      float4 bv = *(const float4*)(Bl + (tl + dg*8 + j)*68 + fq*4);
      acc[j] += a.x*bv.x + a.y*bv.y + a.z*bv.z + a.w*bv.w;
    }
  }
  float* o = corr_pad + ((size_t)(b*H_ + h))*(518*34) + (size_t)(t0 + tl + 3)*34 + (dg*8 + 1);
#pragma unroll
  for (int j = 0; j < 8; j++) o[j] = acc[j];
}

// ---------------- K3: conv + mask + softmax, corr tile staged in LDS ----------------
__global__ __launch_bounds__(256) void k3_conv_softmax(const float* __restrict__ corr_pad,
                                                       const float* __restrict__ wt,
                                                       float* __restrict__ wq){
  int b  = blockIdx.x >> 6;
  int t0 = (blockIdx.x & 63) * 8;
  int tid = threadIdx.x;

  // LDS tile: [h][12 padded rows t0..t0+11][34 d]  (taps for t in [t0,t0+8))
  __shared__ float ls[32*12*34];
  const float* cp = corr_pad + (size_t)b * (H_*518*34);
  for (int idx = tid; idx < 32*12*34; idx += 256){
    int h = idx / 408, rem = idx - h*408;
    int r = rem / 34, dd = rem - r*34;
    ls[idx] = cp[(size_t)h*(518*34) + (size_t)(t0 + r)*34 + dd];
  }
  __syncthreads();

  int tl = tid >> 5, d = tid & 31;
  int t = t0 + tl;

  const float* wcf = wt + 8256;
  float val = wt[8736];

  for (int h = 0; h < H_; h++){
    const float* base = ls + h*408 + tl*34 + d;
    const float* wch = wcf + h*15;
#pragma unroll
    for (int kh = 0; kh < 5; kh++){
#pragma unroll
      for (int kw = 0; kw < 3; kw++){
        val += base[kh*34 + kw] * wch[kh*3 + kw];
      }
    }
  }
  if (t + d < D_ - 1) val = -1e13f;

  float m = val;
#pragma unroll
  for (int off = 16; off > 0; off >>= 1) m = fmaxf(m, __shfl_xor(m, off));
  float e = __expf(val - m);
  float s = e;
#pragma unroll
  for (int off = 16; off > 0; off >>= 1) s += __shfl_xor(s, off);

  wq[((size_t)b*T_ + t)*D_ + d] = e / s;
}

// ---------------- K4: out[b,c,t,f] = sum_d w[b,t,d] * xf[b,c,t+d-31,f] ----------------
__global__ __launch_bounds__(256) void k4_out(const void* __restrict__ xf, const float* __restrict__ wq,
                                              const u32* __restrict__ flag, void* __restrict__ out){
  int blk = blockIdx.x;
  int tt = blk & 7, c = (blk >> 3) & 127, b = blk >> 10;
  int t0 = tt * 64;
  u32 isf = *flag;

  __shared__ float xfl[95*68];
  __shared__ float wl[64*33];
  int tid = threadIdx.x;

  if (!isf){
    const u16* Xf = (const u16*)xf + ((size_t)(b*C_ + c)) * (T_*F_);
    for (int idx = tid; idx < 95*16; idx += 256){
      int r = idx >> 4, q = idx & 15;
      int gr = t0 - 31 + r;
      float4 v = make_float4(0.f,0.f,0.f,0.f);
      if (gr >= 0){
        uint2 u = *(const uint2*)(Xf + (size_t)gr*F_ + q*4);
        v.x = bf_lo(u.x); v.y = bf_hi(u.x); v.z = bf_lo(u.y); v.w = bf_hi(u.y);
      }
      *(float4*)(xfl + r*68 + q*4) = v;
    }
  } else {
    const float* Xf = (const float*)xf + ((size_t)(b*C_ + c)) * (T_*F_);
    for (int idx = tid; idx < 95*16; idx += 256){
      int r = idx >> 4, q = idx & 15;
      int gr = t0 - 31 + r;
      float4 v = make_float4(0.f,0.f,0.f,0.f);
      if (gr >= 0){
        float4 u = *(const float4*)(Xf + (size_t)gr*F_ + q*4);
        v.x = f32s(u.x); v.y = f32s(u.y); v.z = f32s(u.z); v.w = f32s(u.w);
      }
      *(float4*)(xfl + r*68 + q*4) = v;
    }
  }
  for (int idx = tid; idx < 64*8; idx += 256){
    int r = idx >> 3, q = idx & 7;
    float4 v = *(const float4*)(wq + ((size_t)b*T_ + t0 + r)*D_ + q*4);
    wl[r*33 + q*4 + 0] = v.x; wl[r*33 + q*4 + 1] = v.y;
    wl[r*33 + q*4 + 2] = v.z; wl[r*33 + q*4 + 3] = v.w;
  }
  __syncthreads();

  int tg = tid >> 4, q = tid & 15;
  float4 acc[4];
#pragma unroll
  for (int j = 0; j < 4; j++) acc[j] = make_float4(0.f,0.f,0.f,0.f);

#pragma unroll
  for (int rr = 0; rr < 35; rr++){
    float4 xv = *(const float4*)(xfl + (tg*4 + rr)*68 + q*4);
#pragma unroll
    for (int j = 0; j < 4; j++){
      int d = rr - j;
      if (d >= 0 && d < D_){
        float wv = wl[(tg*4 + j)*33 + d];
        acc[j].x += wv * xv.x; acc[j].y += wv * xv.y;
        acc[j].z += wv * xv.z; acc[j].w += wv * xv.w;
      }
    }
  }
  if (!isf){
#pragma unroll
    for (int j = 0; j < 4; j++){
      int t = t0 + tg*4 + j;
      u16* O = (u16*)out + (((size_t)(b*C_ + c))*T_ + t)*F_ + q*4;
      u32 lo = (u32)f2bf(acc[j].x) | ((u32)f2bf(acc[j].y) << 16);
      u32 hi = (u32)f2bf(acc[j].z) | ((u32)f2bf(acc[j].w) << 16);
      *(uint2*)O = make_uint2(lo, hi);
    }
  } else {
#pragma unroll
    for (int j = 0; j < 4; j++){
      int t = t0 + tg*4 + j;
      float* O = (float*)out + (((size_t)(b*C_ + c))*T_ + t)*F_ + q*4;
      *(float4*)O = acc[j];
    }
  }
}

extern "C" void kernel_launch(void* const* d_in, const int* in_sizes, int n_in,
                              void* d_out, int out_size, void* d_ws, size_t ws_size,
                              hipStream_t stream) {
  const void* xm = d_in[0];
  const void* xf = d_in[1];
  float* ws = (float*)d_ws;
  u32* flag = (u32*)(ws + FLAG_OFF);

  float* xm1 = (float*)d_out + XM1_OUT;
  float* xf1 = (float*)d_out + XF1_OUT;

  hipLaunchKernelGGL(kd_detect, dim3(1), dim3(256), 0, stream, (const u16*)d_in[2], flag);
  hipLaunchKernelGGL(k0_init, dim3(1024), dim3(256), 0, stream, d_in[2], d_in[3], d_in[4],
                     d_in[5], d_in[6], d_in[7], ws, flag);
  hipLaunchKernelGGL(k1_proj, dim3(256), dim3(256), 0, stream, xm, xf, ws + WT_OFF, flag, xm1, xf1);
  hipLaunchKernelGGL(k2_corr, dim3(512), dim3(256), 0, stream, xm1, xf1, ws + CORR_OFF);
  hipLaunchKernelGGL(k3_conv_softmax, dim3(128), dim3(256), 0, stream, ws + CORR_OFF,
                     ws + WT_OFF, ws + WQ_OFF);
  hipLaunchKernelGGL(k4_out, dim3(2048), dim3(256), 0, stream, xf, ws + WQ_OFF, flag, d_out);
}